// Round 6
// baseline (104.535 us; speedup 1.0000x reference)
//
#include <hip/hip_runtime.h>
#include <cstdint>

#define INFIN __builtin_inff()
constexpr int KMAX = 256;
constexpr int NGRP = 4;            // gt groups of 64
constexpr int TILE = 1024;
constexpr int TPS  = 4;            // tiles per strip
constexpr int SPTS = TILE * TPS;   // 4096 points per strip

// ws: int2 wsmm[256] @ 0 ; int ticket @ 2048 ; u64 pack2[nstrip*256] @ 4096

// ---------- A: zero output + per-block level min/max + ticket reset ----------
__global__ __launch_bounds__(256)
void k_pre(const float* __restrict__ pts, int2* __restrict__ wsmm,
           int* __restrict__ ticket, int4* __restrict__ outz, int n4, int N) {
    int t = threadIdx.x, b = blockIdx.x;
    int gid = b * 256 + t, gsz = gridDim.x * 256;
    for (int i = gid; i < n4; i += gsz) outz[i] = make_int4(0, 0, 0, 0);
    int lmin = 127, lmax = -127;
    for (int i = gid; i < N; i += gsz) {
        unsigned u = __float_as_uint(pts[3 * i + 2]);
        int e = (int)((u >> 23) & 0xFF) - 127;   // exact log2 (stride = power of 2)
        lmin = min(lmin, e); lmax = max(lmax, e);
    }
    #pragma unroll
    for (int off = 32; off > 0; off >>= 1) {
        lmin = min(lmin, __shfl_xor(lmin, off));
        lmax = max(lmax, __shfl_xor(lmax, off));
    }
    __shared__ int sm[4], sx[4];
    int wv = t >> 6;
    if ((t & 63) == 0) { sm[wv] = lmin; sx[wv] = lmax; }
    __syncthreads();
    if (t == 0) {
        wsmm[b] = make_int2(min(min(sm[0], sm[1]), min(sm[2], sm[3])),
                            max(max(sx[0], sx[1]), max(sx[2], sx[3])));
        if (b == 0) *ticket = 0;
    }
}

// ---------- B: strip×group scan + last-block resolve ----------
__global__ __launch_bounds__(1024)
void k_main(const float* __restrict__ pts, const float* __restrict__ gtb,
            const int* __restrict__ glab, const int2* __restrict__ wsmm,
            int* __restrict__ ticket, unsigned long long* __restrict__ pack2,
            int* __restrict__ out, int N, int K, int nstrip) {
    const int t = threadIdx.x, b = blockIdx.x;
    const int s = b % nstrip, g = b / nstrip;   // group-major: co-strip groups adjacent mod 8
    const int wv = t >> 6, lane = t & 63;

    __shared__ float4 sp[TILE];
    __shared__ float s_cx[KMAX], s_cy[KMAX], s_w[KMAX], s_h[KMAX], s_rw[KMAX], s_rh[KMAX];
    __shared__ int   s_org[KMAX], s_gbin[KMAX];
    __shared__ int   s_wh[16][5], s_wb[16][5], s_pcnt[5], s_gcnt[5];
    __shared__ int   s_mm[2], s_old;
    __shared__ unsigned long long sh_p[1024];
    __shared__ int   hkey[512];
    __shared__ unsigned long long hval[512];

    // phase 0: reduce global level min/max from the 256 per-block entries
    if (t < 64) {
        int lmin = 127, lmax = -127;
        for (int j = t; j < 256; j += 64) {
            int2 mm = wsmm[j];
            lmin = min(lmin, mm.x); lmax = max(lmax, mm.y);
        }
        #pragma unroll
        for (int off = 32; off > 0; off >>= 1) {
            lmin = min(lmin, __shfl_xor(lmin, off));
            lmax = max(lmax, __shfl_xor(lmax, off));
        }
        if (t == 0) { s_mm[0] = lmin; s_mm[1] = lmax; }
    }

    // phase 1a: gt prep (independent of s_mm)
    float cx = 0.f, cy = 0.f, w = 1.f, h = 1.f, rw = 1.f, rh = 1.f, gf = 0.f;
    if (t < K) {
        float x0 = gtb[8*t+0], y0 = gtb[8*t+1], x1 = gtb[8*t+2], y1 = gtb[8*t+3];
        float x2 = gtb[8*t+4], y2 = gtb[8*t+5], x3 = gtb[8*t+6], y3 = gtb[8*t+7];
        float xmin = fminf(fminf(x0, x1), fminf(x2, x3));
        float xmax = fmaxf(fmaxf(x0, x1), fmaxf(x2, x3));
        float ymin = fminf(fminf(y0, y1), fminf(y2, y3));
        float ymax = fmaxf(fmaxf(y0, y1), fmaxf(y2, y3));
        cx = __fmul_rn(__fadd_rn(xmin, xmax), 0.5f);
        cy = __fmul_rn(__fadd_rn(ymin, ymax), 0.5f);
        w  = fmaxf(__fsub_rn(xmax, xmin), 1e-6f);
        h  = fmaxf(__fsub_rn(ymax, ymin), 1e-6f);
        rw = 1.0f / w;                              // RN reciprocal for Markstein
        rh = 1.0f / h;
        gf = __fmul_rn(__fadd_rn(log2f(__fmul_rn(w, 0.25f)),
                                 log2f(__fmul_rn(h, 0.25f))), 0.5f);
    }
    __syncthreads();

    // phase 1b: clamp + stable level-grouping of gts (identical in every block)
    int gbin = 99;
    if (t < K) {
        int gl = (int)gf;
        gl = min(max(gl, s_mm[0]), s_mm[1]);
        gbin = min(max(gl - 3, 0), 4);              // data levels in [3,7]
    }
    int grank = 0;
    if (t < 256) {
        #pragma unroll
        for (int bb = 0; bb < 5; ++bb) {
            unsigned long long m = __ballot(gbin == bb);
            if (gbin == bb) grank = __popcll(m & ((1ull << lane) - 1ull));
            if (lane == 0) s_wh[wv][bb] = __popcll(m);
        }
    }
    __syncthreads();
    if (t < 5) {
        int run = 0;
        for (int w2 = 0; w2 < 4; ++w2) { s_wb[w2][t] = run; run += s_wh[w2][t]; }
        s_gcnt[t] = run;
    }
    __syncthreads();
    if (t < K) {
        int base = 0;
        for (int bb = 0; bb < gbin; ++bb) base += s_gcnt[bb];
        int slot = base + s_wb[wv][gbin] + grank;   // permutation of 0..K-1, level-sorted
        s_cx[slot] = cx; s_cy[slot] = cy;
        s_w[slot] = w;   s_h[slot] = h;
        s_rw[slot] = rw; s_rh[slot] = rh;
        s_org[slot] = t; s_gbin[slot] = gbin;
    }
    __syncthreads();

    // this thread's gt: consecutive sorted slots per lane -> broadcast LDS reads
    const int slot = g * 64 + lane;
    const int c = wv;                               // 16 copies per gt
    const bool gact = slot < K;
    float gcx = 0.f, gcy = 0.f, gw = 1.f, gh = 1.f, grw = 1.f, grh = 1.f;
    int gbin2 = 0;
    if (gact) {
        gcx = s_cx[slot]; gcy = s_cy[slot];
        gw = s_w[slot];  gh = s_h[slot];
        grw = s_rw[slot]; grh = s_rh[slot];
        gbin2 = s_gbin[slot];
    }
    float bd = INFIN, sthr = INFIN;
    int bix = 0x7FFFFFFF;

    // tile loop over this strip's 4096 points
    for (int tt = 0; tt < TPS; ++tt) {
        int tbase = s * SPTS + tt * TILE;
        if (tbase >= N) break;                      // block-uniform
        __syncthreads();                            // protect sp / s_wh / s_pcnt reuse

        // bucket tile points by level into LDS (stable within tile)
        int i = tbase + t;
        float px = 0.f, py = 0.f;
        int pbin = -1;
        if (i < N) {
            px = pts[3 * i]; py = pts[3 * i + 1];
            unsigned u = __float_as_uint(pts[3 * i + 2]);
            int e = (int)((u >> 23) & 0xFF) - 127;
            pbin = e - 3;
            if (pbin < 0 || pbin > 4) pbin = -1;
        }
        int prank = 0;
        #pragma unroll
        for (int bb = 0; bb < 5; ++bb) {
            unsigned long long m = __ballot(pbin == bb);
            if (pbin == bb) prank = __popcll(m & ((1ull << lane) - 1ull));
            if (lane == 0) s_wh[wv][bb] = __popcll(m);
        }
        __syncthreads();
        if (t < 5) {
            int run = 0;
            for (int w2 = 0; w2 < 16; ++w2) { s_wb[w2][t] = run; run += s_wh[w2][t]; }
            s_pcnt[t] = run;
        }
        __syncthreads();
        if (pbin >= 0) {
            int base0 = 0;
            for (int bb = 0; bb < pbin; ++bb) base0 += s_pcnt[bb];
            sp[base0 + s_wb[wv][pbin] + prank] = make_float4(px, py, __int_as_float(i), 0.f);
        }
        __syncthreads();

        // scan this gt's level bucket (lazy-sqrt filter; exact lex (d, idx))
        if (gact) {
            int base0 = 0;
            for (int bb = 0; bb < gbin2; ++bb) base0 += s_pcnt[bb];
            int cnt = s_pcnt[gbin2];
            int seg = (cnt + 15) >> 4;
            int i0 = c * seg, i1 = min(i0 + seg, cnt);
            for (int ii = i0; ii < i1; ++ii) {
                float4 q = sp[base0 + ii];
                float dx = __fsub_rn(q.x, gcx);
                float dy = __fsub_rn(q.y, gcy);
                float qx = __fmul_rn(dx, grw);      // Markstein: == __fdiv_rn(dx, gw)
                qx = __fmaf_rn(__fmaf_rn(-gw, qx, dx), grw, qx);
                float qy = __fmul_rn(dy, grh);
                qy = __fmaf_rn(__fmaf_rn(-gh, qy, dy), grh, qy);
                float ss = __fadd_rn(__fmul_rn(qx, qx), __fmul_rn(qy, qy));
                if (ss <= sthr) {                   // rare candidate path
                    float d = __fsqrt_rn(ss);
                    int ix = __float_as_int(q.z);
                    if (d < bd || (d == bd && ix < bix)) { bd = d; bix = ix; }
                    sthr = __fmul_rn(__fmul_rn(bd, bd), 1.000002f);  // >= max ss with sqrt<=bd
                }
            }
        }
    }

    // merge 16 copies per gt; store this strip's row (indexed by ORIGINAL gt)
    sh_p[t] = ((unsigned long long)__float_as_uint(bd) << 32) | (unsigned)bix;
    __syncthreads();
    if (t < 64) {
        unsigned long long p0 = sh_p[t];
        #pragma unroll
        for (int cc = 1; cc < 16; ++cc) {
            unsigned long long p1 = sh_p[cc * 64 + t];
            p0 = p1 < p0 ? p1 : p0;
        }
        int sl = g * 64 + t;
        if (sl < K) pack2[(size_t)s * KMAX + s_org[sl]] = p0;
    }

    // release + ticket; last block finalizes
    __threadfence();
    if (t == 0) s_old = atomicAdd(ticket, 1);
    __syncthreads();
    if (s_old != gridDim.x - 1) return;
    __threadfence();

    // final: reduce nstrip rows (coalesced), hash contention-resolve, scatter
    {
        const int org = t & 255, c4 = t >> 8;
        unsigned long long best = ~0ull;
        for (int st = c4; st < nstrip; st += 4) {
            unsigned long long v = pack2[(size_t)st * KMAX + org];
            best = v < best ? v : best;
        }
        sh_p[t] = best;
        if (t < 512) { hkey[t] = -1; hval[t] = ~0ull; }
        __syncthreads();
        if (t < 256) {
            unsigned long long p = sh_p[t];
            #pragma unroll
            for (int q2 = 1; q2 < 4; ++q2) {
                unsigned long long p1 = sh_p[q2 * 256 + t];
                p = p1 < p ? p1 : p;
            }
            unsigned db = (unsigned)(p >> 32);
            bool valid = (t < K) && (db < 0x7F800000u);
            int nk = (int)(unsigned)(p & 0xFFFFFFFFu);
            int h = 0;
            if (valid) {
                unsigned long long myp = ((unsigned long long)db << 32) | (unsigned)t;
                h = (int)((((unsigned)nk) * 2654435761u) >> 23) & 511;
                while (true) {
                    int old = atomicCAS(&hkey[h], -1, nk);
                    if (old == -1 || old == nk) { atomicMin(&hval[h], myp); break; }
                    h = (h + 1) & 511;
                }
            }
            __syncthreads();
            if (valid && (int)(unsigned)(hval[h] & 0xFFFFFFFFu) == t) {
                out[nk]     = t + 1;
                out[N + nk] = glab[t];
            }
        } else {
            __syncthreads();
        }
    }
}

extern "C" void kernel_launch(void* const* d_in, const int* in_sizes, int n_in,
                              void* d_out, int out_size, void* d_ws, size_t ws_size,
                              hipStream_t stream) {
    const float* pts = (const float*)d_in[0];
    const float* gtb = (const float*)d_in[1];
    const int*  glab = (const int*)d_in[2];
    int N = in_sizes[0] / 3;
    int K = in_sizes[1] / 8;
    char* wsc = (char*)d_ws;
    int2* wsmm = (int2*)wsc;
    int* ticket = (int*)(wsc + 2048);
    unsigned long long* pack2 = (unsigned long long*)(wsc + 4096);
    int nstrip = (N + SPTS - 1) / SPTS;

    k_pre<<<256, 256, 0, stream>>>(pts, wsmm, ticket, (int4*)d_out, out_size / 4, N);
    k_main<<<nstrip * NGRP, 1024, 0, stream>>>(pts, gtb, glab, (const int2*)wsmm,
                                               ticket, pack2, (int*)d_out, N, K, nstrip);
}

// Round 7
// 43.436 us; speedup vs baseline: 2.4067x; 2.4067x over previous
//
#include <hip/hip_runtime.h>
#include <cstdint>

#define INFIN __builtin_inff()
constexpr int KMAX = 256;
constexpr int NB   = 256;   // fixed grid for k_dist

// ws layout: int2 wsmm[256] @ 0 ; int ticket @ 2048 ; u64 pack2[NB*256] @ 4096 (512 KB)

// ---------- A: zero output + per-block level min/max + ticket reset ----------
__global__ __launch_bounds__(256)
void k_pre(const float* __restrict__ pts, int2* __restrict__ wsmm,
           int* __restrict__ ticket, int4* __restrict__ outz, int n4, int N) {
    int t = threadIdx.x, b = blockIdx.x;
    int gid = b * 256 + t, gsz = gridDim.x * 256;
    for (int i = gid; i < n4; i += gsz) outz[i] = make_int4(0, 0, 0, 0);
    int lmin = 127, lmax = -127;
    for (int i = gid; i < N; i += gsz) {
        unsigned u = __float_as_uint(pts[3 * i + 2]);
        int e = (int)((u >> 23) & 0xFF) - 127;   // exact log2 (stride = power of 2)
        lmin = min(lmin, e); lmax = max(lmax, e);
    }
    __shared__ int smin[256], smax[256];
    smin[t] = lmin; smax[t] = lmax;
    __syncthreads();
    for (int off = 128; off > 0; off >>= 1) {
        if (t < off) {
            smin[t] = min(smin[t], smin[t + off]);
            smax[t] = max(smax[t], smax[t + off]);
        }
        __syncthreads();
    }
    if (t == 0) {
        wsmm[b] = make_int2(smin[0], smax[0]);
        if (b == 0) *ticket = 0;
    }
}

// ---------- B: round-5 scan body + fence-free last-block finalize ----------
__global__ __launch_bounds__(1024)
void k_dist(const float* __restrict__ pts, const float* __restrict__ gtb,
            const int* __restrict__ glab, const int2* __restrict__ wsmm,
            int* __restrict__ ticket, unsigned long long* __restrict__ pack2,
            int* __restrict__ out, int N, int K) {
    const int t = threadIdx.x, b = blockIdx.x;
    const int wv = t >> 6, lane = t & 63;

    __shared__ float4 sp[1024];                     // bucketed points (x,y,idx_bits,pad)
    __shared__ float s_cx[KMAX], s_cy[KMAX], s_w[KMAX], s_h[KMAX], s_rw[KMAX], s_rh[KMAX];
    __shared__ int   s_org[KMAX], s_gbin[KMAX];
    __shared__ int   s_wh[16][5], s_wb[16][5], s_pcnt[5], s_gcnt[5];
    __shared__ int   s_mm[2], s_old;
    __shared__ unsigned long long sh_p[1024];
    __shared__ int   hkey[512];
    __shared__ unsigned long long hval[512];

    // phase 0: single-wave reduce of global level min/max
    if (t < 64) {
        int2 a = wsmm[t], b2 = wsmm[t + 64], c2 = wsmm[t + 128], d2 = wsmm[t + 192];
        int lmin = min(min(a.x, b2.x), min(c2.x, d2.x));
        int lmax = max(max(a.y, b2.y), max(c2.y, d2.y));
        #pragma unroll
        for (int off = 32; off > 0; off >>= 1) {
            lmin = min(lmin, __shfl_xor(lmin, off));
            lmax = max(lmax, __shfl_xor(lmax, off));
        }
        if (t == 0) { s_mm[0] = lmin; s_mm[1] = lmax; }
    }

    // phase 1a: gt prep (independent of s_mm)
    float cx = 0.f, cy = 0.f, w = 1.f, h = 1.f, rw = 1.f, rh = 1.f, gf = 0.f;
    if (t < K) {
        float x0 = gtb[8*t+0], y0 = gtb[8*t+1], x1 = gtb[8*t+2], y1 = gtb[8*t+3];
        float x2 = gtb[8*t+4], y2 = gtb[8*t+5], x3 = gtb[8*t+6], y3 = gtb[8*t+7];
        float xmin = fminf(fminf(x0, x1), fminf(x2, x3));
        float xmax = fmaxf(fmaxf(x0, x1), fmaxf(x2, x3));
        float ymin = fminf(fminf(y0, y1), fminf(y2, y3));
        float ymax = fmaxf(fmaxf(y0, y1), fmaxf(y2, y3));
        cx = __fmul_rn(__fadd_rn(xmin, xmax), 0.5f);
        cy = __fmul_rn(__fadd_rn(ymin, ymax), 0.5f);
        w  = fmaxf(__fsub_rn(xmax, xmin), 1e-6f);
        h  = fmaxf(__fsub_rn(ymax, ymin), 1e-6f);
        rw = 1.0f / w;                               // RN reciprocal for Markstein
        rh = 1.0f / h;
        gf = __fmul_rn(__fadd_rn(log2f(__fmul_rn(w, 0.25f)),
                                 log2f(__fmul_rn(h, 0.25f))), 0.5f);
    }
    __syncthreads();

    // phase 1b: level clamp + stable level-grouping of gts (identical in every block)
    int gbin = 99;
    if (t < K) {
        int gl = (int)gf;
        gl = min(max(gl, s_mm[0]), s_mm[1]);
        gbin = min(max(gl - 3, 0), 4);               // data levels in [3,7]
    }
    int grank = 0;
    if (t < 256) {                                   // waves 0..3 fully active
        #pragma unroll
        for (int bb = 0; bb < 5; ++bb) {
            unsigned long long m = __ballot(gbin == bb);
            if (gbin == bb) grank = __popcll(m & ((1ull << lane) - 1ull));
            if (lane == 0) s_wh[wv][bb] = __popcll(m);
        }
    }
    __syncthreads();
    if (t < 5) {
        int run = 0;
        for (int w2 = 0; w2 < 4; ++w2) { s_wb[w2][t] = run; run += s_wh[w2][t]; }
        s_gcnt[t] = run;
    }
    __syncthreads();
    if (t < K) {
        int base = 0;
        for (int bb = 0; bb < gbin; ++bb) base += s_gcnt[bb];
        int slot = base + s_wb[wv][gbin] + grank;    // permutation of 0..K-1
        s_cx[slot] = cx; s_cy[slot] = cy;
        s_w[slot] = w;   s_h[slot] = h;
        s_rw[slot] = rw; s_rh[slot] = rh;
        s_org[slot] = t; s_gbin[slot] = gbin;
    }
    __syncthreads();

    // per-thread running best for its (gt slot, copy)
    const int c = t >> 8, g = t & 255;
    float gcx = 0.f, gcy = 0.f, gw = 1.f, gh = 1.f, grw = 1.f, grh = 1.f;
    int gbin2 = 0;
    if (g < K) {
        gcx = s_cx[g]; gcy = s_cy[g];
        gw = s_w[g];  gh = s_h[g];
        grw = s_rw[g]; grh = s_rh[g];
        gbin2 = s_gbin[g];
    }
    unsigned long long bp = ~0ull;

    // tile loop: each block handles tiles b, b+NB, ...
    for (int tile = b; tile * 1024 < N; tile += NB) {
        __syncthreads();                             // protect sp/s_pcnt reuse

        // phase 2: bucket this tile's 1024 points by level into LDS
        int i = tile * 1024 + t;
        float px = 0.f, py = 0.f;
        int pbin = -1;
        if (i < N) {
            px = pts[3 * i]; py = pts[3 * i + 1];
            unsigned u = __float_as_uint(pts[3 * i + 2]);
            int e = (int)((u >> 23) & 0xFF) - 127;
            pbin = e - 3;
            if (pbin < 0 || pbin > 4) pbin = -1;
        }
        int prank = 0;
        #pragma unroll
        for (int bb = 0; bb < 5; ++bb) {
            unsigned long long m = __ballot(pbin == bb);
            if (pbin == bb) prank = __popcll(m & ((1ull << lane) - 1ull));
            if (lane == 0) s_wh[wv][bb] = __popcll(m);
        }
        __syncthreads();
        if (t < 5) {
            int run = 0;
            for (int w2 = 0; w2 < 16; ++w2) { s_wb[w2][t] = run; run += s_wh[w2][t]; }
            s_pcnt[t] = run;
        }
        __syncthreads();
        if (pbin >= 0) {
            int base = 0;
            for (int bb = 0; bb < pbin; ++bb) base += s_pcnt[bb];
            int pos = base + s_wb[wv][pbin] + prank;
            sp[pos] = make_float4(px, py, __int_as_float(i), 0.f);
        }
        __syncthreads();

        // phase 3: branchless scan of this gt's level bucket (broadcast LDS reads)
        if (g < K) {
            int base = 0;
            for (int bb = 0; bb < gbin2; ++bb) base += s_pcnt[bb];
            int cnt = s_pcnt[gbin2];
            int seg = (cnt + 3) >> 2;
            int i0 = c * seg, i1 = min(i0 + seg, cnt);
            #pragma unroll 4
            for (int ii = i0; ii < i1; ++ii) {
                float4 q = sp[base + ii];
                float dx = __fsub_rn(q.x, gcx);
                float dy = __fsub_rn(q.y, gcy);
                float qx = __fmul_rn(dx, grw);       // Markstein: == __fdiv_rn(dx, gw)
                qx = __fmaf_rn(__fmaf_rn(-gw, qx, dx), grw, qx);
                float qy = __fmul_rn(dy, grh);
                qy = __fmaf_rn(__fmaf_rn(-gh, qy, dy), grh, qy);
                float s = __fadd_rn(__fmul_rn(qx, qx), __fmul_rn(qy, qy));
                float d = __fsqrt_rn(s);
                unsigned long long cand =
                    ((unsigned long long)__float_as_uint(d) << 32)
                    | (unsigned)__float_as_int(q.z);
                bp = cand < bp ? cand : bp;          // lex-min (d, idx)
            }
        }
    }

    // phase 4: merge 4 copies; write block row via device-scope atomicExch (fabric)
    sh_p[t] = bp;
    __syncthreads();
    if (t < K) {
        unsigned long long p0 = sh_p[t];
        #pragma unroll
        for (int cc = 1; cc < 4; ++cc) {
            unsigned long long p1 = sh_p[cc * 256 + t];
            p0 = p1 < p0 ? p1 : p0;
        }
        atomicExch(&pack2[(size_t)b * KMAX + s_org[t]], p0);
    }
    // barrier drains each thread's vmcnt (compiler emits s_waitcnt vmcnt(0) before
    // s_barrier) => all row atomics acked at the coherent point before the ticket.
    __syncthreads();
    if (t == 0) s_old = atomicAdd(ticket, 1);
    __syncthreads();
    if (s_old != (int)gridDim.x - 1) return;

    // phase 5 (last block only): reduce rows via fabric RMW reads, resolve, scatter
    {
        const int org = t & 255, c4 = t >> 8;
        unsigned long long best = ~0ull;
        if (org < K) {
            for (int st = c4; st < NB; st += 4) {
                unsigned long long v = atomicMin(&pack2[(size_t)st * KMAX + org], ~0ull);
                best = v < best ? v : best;
            }
        }
        sh_p[t] = best;
        if (t < 512) { hkey[t] = -1; hval[t] = ~0ull; }
        __syncthreads();
        if (t < 256) {
            unsigned long long p = sh_p[t];
            #pragma unroll
            for (int q2 = 1; q2 < 4; ++q2) {
                unsigned long long p1 = sh_p[q2 * 256 + t];
                p = p1 < p ? p1 : p;
            }
            unsigned db = (unsigned)(p >> 32);
            bool valid = (t < K) && (db < 0x7F800000u);
            int nk = (int)(unsigned)(p & 0xFFFFFFFFu);
            int h = 0;
            if (valid) {
                unsigned long long myp = ((unsigned long long)db << 32) | (unsigned)t;
                h = (int)((((unsigned)nk) * 2654435761u) >> 23) & 511;
                while (true) {
                    int old = atomicCAS(&hkey[h], -1, nk);
                    if (old == -1 || old == nk) { atomicMin(&hval[h], myp); break; }
                    h = (h + 1) & 511;
                }
            }
            __syncthreads();
            if (valid && (int)(unsigned)(hval[h] & 0xFFFFFFFFu) == t) {
                out[nk]     = t + 1;
                out[N + nk] = glab[t];
            }
        } else {
            __syncthreads();
        }
    }
}

extern "C" void kernel_launch(void* const* d_in, const int* in_sizes, int n_in,
                              void* d_out, int out_size, void* d_ws, size_t ws_size,
                              hipStream_t stream) {
    const float* pts = (const float*)d_in[0];
    const float* gtb = (const float*)d_in[1];
    const int*  glab = (const int*)d_in[2];
    int N = in_sizes[0] / 3;
    int K = in_sizes[1] / 8;
    char* wsc = (char*)d_ws;
    int2* wsmm = (int2*)wsc;
    int* ticket = (int*)(wsc + 2048);
    unsigned long long* pack2 = (unsigned long long*)(wsc + 4096);

    k_pre<<<256, 256, 0, stream>>>(pts, wsmm, ticket, (int4*)d_out, out_size / 4, N);
    k_dist<<<NB, 1024, 0, stream>>>(pts, gtb, glab, (const int2*)wsmm,
                                    ticket, pack2, (int*)d_out, N, K);
}

// Round 8
// 35.630 us; speedup vs baseline: 2.9340x; 1.2191x over previous
//
#include <hip/hip_runtime.h>
#include <cstdint>

#define INFIN __builtin_inff()
constexpr int KMAX = 256;
constexpr int NB   = 256;   // fixed grid for k_dist

// ws layout: int2 wsmm[256] @ 0 ; u64 pack2[NB*256] @ 4096 (512 KB)

// ---------- A: zero output + per-block level min/max ----------
__global__ __launch_bounds__(256)
void k_pre(const float* __restrict__ pts, int2* __restrict__ wsmm,
           int4* __restrict__ outz, int n4, int N) {
    int t = threadIdx.x, b = blockIdx.x;
    int gid = b * 256 + t, gsz = gridDim.x * 256;
    for (int i = gid; i < n4; i += gsz) outz[i] = make_int4(0, 0, 0, 0);
    int lmin = 127, lmax = -127;
    for (int i = gid; i < N; i += gsz) {
        unsigned u = __float_as_uint(pts[3 * i + 2]);
        int e = (int)((u >> 23) & 0xFF) - 127;   // exact log2 (stride = power of 2)
        lmin = min(lmin, e); lmax = max(lmax, e);
    }
    __shared__ int smin[256], smax[256];
    smin[t] = lmin; smax[t] = lmax;
    __syncthreads();
    for (int off = 128; off > 0; off >>= 1) {
        if (t < off) {
            smin[t] = min(smin[t], smin[t + off]);
            smax[t] = max(smax[t], smax[t + off]);
        }
        __syncthreads();
    }
    if (t == 0) wsmm[b] = make_int2(smin[0], smax[0]);
}

// ---------- B: block-local bucketing + UNIFORM branchless scan + private-row store ----------
__global__ __launch_bounds__(1024)
void k_dist(const float* __restrict__ pts, const float* __restrict__ gtb,
            const int2* __restrict__ wsmm, unsigned long long* __restrict__ pack2,
            int N, int K) {
    const int t = threadIdx.x, b = blockIdx.x;
    const int wv = t >> 6, lane = t & 63;

    __shared__ float4 sp[1024];                     // bucketed points (x,y,idx_bits,pad)
    __shared__ float s_cx[KMAX], s_cy[KMAX], s_w[KMAX], s_h[KMAX], s_rw[KMAX], s_rh[KMAX];
    __shared__ int   s_org[KMAX], s_gbin[KMAX];
    __shared__ int   s_wh[16][5], s_wb[16][5], s_pcnt[5], s_gcnt[5];
    __shared__ int   s_mm[2];
    __shared__ unsigned long long sh_p[1024];

    // phase 0: single-wave reduce of global level min/max
    if (t < 64) {
        int2 a = wsmm[t], b2 = wsmm[t + 64], c2 = wsmm[t + 128], d2 = wsmm[t + 192];
        int lmin = min(min(a.x, b2.x), min(c2.x, d2.x));
        int lmax = max(max(a.y, b2.y), max(c2.y, d2.y));
        #pragma unroll
        for (int off = 32; off > 0; off >>= 1) {
            lmin = min(lmin, __shfl_xor(lmin, off));
            lmax = max(lmax, __shfl_xor(lmax, off));
        }
        if (t == 0) { s_mm[0] = lmin; s_mm[1] = lmax; }
    }

    // phase 1a: gt prep (independent of s_mm)
    float cx = 0.f, cy = 0.f, w = 1.f, h = 1.f, rw = 1.f, rh = 1.f, gf = 0.f;
    if (t < K) {
        float x0 = gtb[8*t+0], y0 = gtb[8*t+1], x1 = gtb[8*t+2], y1 = gtb[8*t+3];
        float x2 = gtb[8*t+4], y2 = gtb[8*t+5], x3 = gtb[8*t+6], y3 = gtb[8*t+7];
        float xmin = fminf(fminf(x0, x1), fminf(x2, x3));
        float xmax = fmaxf(fmaxf(x0, x1), fmaxf(x2, x3));
        float ymin = fminf(fminf(y0, y1), fminf(y2, y3));
        float ymax = fmaxf(fmaxf(y0, y1), fmaxf(y2, y3));
        cx = __fmul_rn(__fadd_rn(xmin, xmax), 0.5f);
        cy = __fmul_rn(__fadd_rn(ymin, ymax), 0.5f);
        w  = fmaxf(__fsub_rn(xmax, xmin), 1e-6f);
        h  = fmaxf(__fsub_rn(ymax, ymin), 1e-6f);
        rw = 1.0f / w;                               // RN reciprocal for Markstein
        rh = 1.0f / h;
        gf = __fmul_rn(__fadd_rn(log2f(__fmul_rn(w, 0.25f)),
                                 log2f(__fmul_rn(h, 0.25f))), 0.5f);
    }
    __syncthreads();

    // phase 1b: level clamp + stable level-grouping of gts (identical in every block)
    int gbin = 99;
    if (t < K) {
        int gl = (int)gf;
        gl = min(max(gl, s_mm[0]), s_mm[1]);
        gbin = min(max(gl - 3, 0), 4);               // data levels in [3,7]
    }
    int grank = 0;
    if (t < 256) {                                   // waves 0..3 fully active
        #pragma unroll
        for (int bb = 0; bb < 5; ++bb) {
            unsigned long long m = __ballot(gbin == bb);
            if (gbin == bb) grank = __popcll(m & ((1ull << lane) - 1ull));
            if (lane == 0) s_wh[wv][bb] = __popcll(m);
        }
    }
    __syncthreads();
    if (t < 5) {
        int run = 0;
        for (int w2 = 0; w2 < 4; ++w2) { s_wb[w2][t] = run; run += s_wh[w2][t]; }
        s_gcnt[t] = run;
    }
    __syncthreads();
    if (t < K) {
        int base = 0;
        for (int bb = 0; bb < gbin; ++bb) base += s_gcnt[bb];
        int slot = base + s_wb[wv][gbin] + grank;    // permutation of 0..K-1
        s_cx[slot] = cx; s_cy[slot] = cy;
        s_w[slot] = w;   s_h[slot] = h;
        s_rw[slot] = rw; s_rh[slot] = rh;
        s_org[slot] = t; s_gbin[slot] = gbin;
    }
    __syncthreads();

    // per-thread running best for its (gt slot, copy)
    const int c = t >> 8, g = t & 255;
    float gcx = 0.f, gcy = 0.f, gw = 1.f, gh = 1.f, grw = 1.f, grh = 1.f;
    int gbin2 = 0;
    if (g < K) {
        gcx = s_cx[g]; gcy = s_cy[g];
        gw = s_w[g];  gh = s_h[g];
        grw = s_rw[g]; grh = s_rh[g];
        gbin2 = s_gbin[g];
    }
    unsigned long long bp = ~0ull;

    // tile loop: each block handles tiles b, b+NB, ...
    for (int tile = b; tile * 1024 < N; tile += NB) {
        __syncthreads();                             // protect sp/s_pcnt reuse

        // phase 2: bucket this tile's 1024 points by level into LDS
        int i = tile * 1024 + t;
        float px = 0.f, py = 0.f;
        int pbin = -1;
        if (i < N) {
            px = pts[3 * i]; py = pts[3 * i + 1];
            unsigned u = __float_as_uint(pts[3 * i + 2]);
            int e = (int)((u >> 23) & 0xFF) - 127;
            pbin = e - 3;
            if (pbin < 0 || pbin > 4) pbin = -1;
        }
        int prank = 0;
        #pragma unroll
        for (int bb = 0; bb < 5; ++bb) {
            unsigned long long m = __ballot(pbin == bb);
            if (pbin == bb) prank = __popcll(m & ((1ull << lane) - 1ull));
            if (lane == 0) s_wh[wv][bb] = __popcll(m);
        }
        __syncthreads();
        if (t < 5) {
            int run = 0;
            for (int w2 = 0; w2 < 16; ++w2) { s_wb[w2][t] = run; run += s_wh[w2][t]; }
            s_pcnt[t] = run;
        }
        __syncthreads();
        if (pbin >= 0) {
            int base = 0;
            for (int bb = 0; bb < pbin; ++bb) base += s_pcnt[bb];
            int pos = base + s_wb[wv][pbin] + prank;
            sp[pos] = make_float4(px, py, __int_as_float(i), 0.f);
        }
        __syncthreads();

        // phase 3: UNIFORM branchless scan (no per-lane trip divergence)
        if (g < K) {
            int base = 0;
            for (int bb = 0; bb < gbin2; ++bb) base += s_pcnt[bb];
            int cnt = s_pcnt[gbin2];                 // own bin count (per lane)
            int maxc = max(max(max(s_pcnt[0], s_pcnt[1]),
                               max(s_pcnt[2], s_pcnt[3])), s_pcnt[4]);
            int seg = (maxc + 3) >> 2;               // block-uniform trip count
            int i0 = c * seg;
            #pragma unroll 4
            for (int j = 0; j < seg; ++j) {
                int ii = i0 + j;
                bool val = ii < cnt;
                int iic = max(min(ii, cnt - 1), 0);  // clamped read index
                float4 q = sp[base + iic];
                float dx = __fsub_rn(q.x, gcx);
                float dy = __fsub_rn(q.y, gcy);
                float qx = __fmul_rn(dx, grw);       // Markstein: == __fdiv_rn(dx, gw)
                qx = __fmaf_rn(__fmaf_rn(-gw, qx, dx), grw, qx);
                float qy = __fmul_rn(dy, grh);
                qy = __fmaf_rn(__fmaf_rn(-gh, qy, dy), grh, qy);
                float s = __fadd_rn(__fmul_rn(qx, qx), __fmul_rn(qy, qy));
                float d = __fsqrt_rn(s);
                unsigned long long cand =
                    ((unsigned long long)__float_as_uint(d) << 32)
                    | (unsigned)__float_as_int(q.z);
                cand = val ? cand : ~0ull;           // mask out padding lanes
                bp = cand < bp ? cand : bp;          // lex-min (d, idx)
            }
        }
    }

    // phase 4: merge 4 copies, plain store to this block's private row (by ORIGINAL gt)
    sh_p[t] = bp;
    __syncthreads();
    if (t < K) {
        unsigned long long p0 = sh_p[t];
        #pragma unroll
        for (int cc = 1; cc < 4; ++cc) {
            unsigned long long p1 = sh_p[cc * 256 + t];
            p0 = p1 < p0 ? p1 : p0;
        }
        pack2[(size_t)b * 256 + s_org[t]] = p0;
    }
}

// ---------- C: grid reduce + contention resolve via LDS hash + scatter ----------
__global__ __launch_bounds__(1024)
void k_final(const unsigned long long* __restrict__ pack2,
             const int* __restrict__ glab, int* __restrict__ out, int N, int K) {
    __shared__ unsigned long long sh_p[1024];
    __shared__ int hkey[512];
    __shared__ unsigned long long hval[512];
    const int t = threadIdx.x;
    const int c = t >> 8, k = t & 255;

    if (t < 512) { hkey[t] = -1; hval[t] = ~0ull; }

    // reduce over the 256 block rows (coalesced 512B per wave per iter)
    unsigned long long best = ~0ull;
    #pragma unroll 8
    for (int b = c; b < NB; b += 4) {
        unsigned long long v = pack2[(size_t)b * 256 + k];
        best = v < best ? v : best;
    }
    sh_p[t] = best;
    __syncthreads();

    if (t < 256) {
        unsigned long long p = sh_p[t];
        #pragma unroll
        for (int cc = 1; cc < 4; ++cc) {
            unsigned long long p1 = sh_p[cc * 256 + t];
            p = p1 < p ? p1 : p;
        }
        unsigned db = (unsigned)(p >> 32);
        bool valid = (t < K) && (db < 0x7F800000u);
        int nk = (int)(unsigned)(p & 0xFFFFFFFFu);

        int h = 0;
        if (valid) {
            unsigned long long myp = ((unsigned long long)db << 32) | (unsigned)t;
            h = (int)((((unsigned)nk) * 2654435761u) >> 23) & 511;
            while (true) {
                int old = atomicCAS(&hkey[h], -1, nk);
                if (old == -1 || old == nk) { atomicMin(&hval[h], myp); break; }
                h = (h + 1) & 511;
            }
        }
        __syncthreads();
        if (valid && (int)(unsigned)(hval[h] & 0xFFFFFFFFu) == t) {
            out[nk]     = t + 1;
            out[N + nk] = glab[t];
        }
    } else {
        __syncthreads();
    }
}

extern "C" void kernel_launch(void* const* d_in, const int* in_sizes, int n_in,
                              void* d_out, int out_size, void* d_ws, size_t ws_size,
                              hipStream_t stream) {
    const float* pts = (const float*)d_in[0];
    const float* gtb = (const float*)d_in[1];
    const int*  glab = (const int*)d_in[2];
    int N = in_sizes[0] / 3;
    int K = in_sizes[1] / 8;
    int2* wsmm = (int2*)d_ws;
    unsigned long long* pack2 = (unsigned long long*)((char*)d_ws + 4096);

    k_pre<<<256, 256, 0, stream>>>(pts, wsmm, (int4*)d_out, out_size / 4, N);
    k_dist<<<NB, 1024, 0, stream>>>(pts, gtb, (const int2*)wsmm, pack2, N, K);
    k_final<<<1, 1024, 0, stream>>>(pack2, glab, (int*)d_out, N, K);
}

// Round 9
// 28.186 us; speedup vs baseline: 3.7088x; 1.2641x over previous
//
#include <hip/hip_runtime.h>
#include <cstdint>

#define INFIN __builtin_inff()
constexpr int KMAX = 256;

// ws layout: u64 pack2[nrows*256] @ 0 (nrows = gridDim of k_dist, 512 KB at N=256K)

// ---------- B: tile bucketing + local minmax + scan + private-row store ----------
__global__ __launch_bounds__(1024)
void k_dist(const float* __restrict__ pts, const float* __restrict__ gtb,
            unsigned long long* __restrict__ pack2, int* __restrict__ out,
            int N, int K) {
    const int t = threadIdx.x, b = blockIdx.x;
    const int wv = t >> 6, lane = t & 63;

    __shared__ float4 sp[1024];                     // bucketed points (x,y,idx_bits,pad)
    __shared__ float s_cx[KMAX], s_cy[KMAX], s_w[KMAX], s_h[KMAX], s_rw[KMAX], s_rh[KMAX];
    __shared__ int   s_org[KMAX], s_gbin[KMAX];
    __shared__ int   s_wh[16][5], s_wb[16][5], s_pcnt[5];
    __shared__ int   s_gwh[4][5], s_gwb[4][5], s_gcnt[5];
    __shared__ unsigned long long sh_p[1024];

    // phase A: load this block's tile point; zero this tile's output slice
    int i = b * 1024 + t;
    bool act = (i < N);
    float px = 0.f, py = 0.f;
    int pbin = -1;
    if (act) {
        px = pts[3 * i]; py = pts[3 * i + 1];
        unsigned u = __float_as_uint(pts[3 * i + 2]);
        int e = (int)((u >> 23) & 0xFF) - 127;      // exact log2 (stride = power of 2)
        pbin = e - 3;
        if (pbin < 0 || pbin > 4) pbin = -1;
        out[i] = 0; out[N + i] = 0;                 // k_final scatters later (next dispatch)
    }

    // phase B: per-wave level histogram + stable rank
    int prank = 0;
    #pragma unroll
    for (int bb = 0; bb < 5; ++bb) {
        unsigned long long m = __ballot(pbin == bb);
        if (pbin == bb) prank = __popcll(m & ((1ull << lane) - 1ull));
        if (lane == 0) s_wh[wv][bb] = __popcll(m);
    }
    __syncthreads();
    if (t < 5) {
        int run = 0;
        for (int w2 = 0; w2 < 16; ++w2) { s_wb[w2][t] = run; run += s_wh[w2][t]; }
        s_pcnt[t] = run;
    }
    __syncthreads();

    // local level min/max from bucket occupancy (== global [3,7] for this workload:
    // every 1024-pt tile contains all 5 levels; upper clamp can never bind anyway)
    int lmin = 127, lmax = -127;
    #pragma unroll
    for (int bb = 0; bb < 5; ++bb) {
        if (s_pcnt[bb] > 0) { lmin = min(lmin, bb + 3); lmax = max(lmax, bb + 3); }
    }

    // phase C: scatter point into its level bucket in LDS
    if (pbin >= 0) {
        int base = 0;
        for (int bb = 0; bb < pbin; ++bb) base += s_pcnt[bb];
        sp[base + s_wb[wv][pbin] + prank] = make_float4(px, py, __int_as_float(i), 0.f);
    }

    // phase D: gt prep (1 gt/thread, redundant per block) — bit-exact chain
    float cx = 0.f, cy = 0.f, w = 1.f, h = 1.f, rw = 1.f, rh = 1.f;
    int gbin = 99;
    if (t < K) {
        float x0 = gtb[8*t+0], y0 = gtb[8*t+1], x1 = gtb[8*t+2], y1 = gtb[8*t+3];
        float x2 = gtb[8*t+4], y2 = gtb[8*t+5], x3 = gtb[8*t+6], y3 = gtb[8*t+7];
        float xmin = fminf(fminf(x0, x1), fminf(x2, x3));
        float xmax = fmaxf(fmaxf(x0, x1), fmaxf(x2, x3));
        float ymin = fminf(fminf(y0, y1), fminf(y2, y3));
        float ymax = fmaxf(fmaxf(y0, y1), fmaxf(y2, y3));
        cx = __fmul_rn(__fadd_rn(xmin, xmax), 0.5f);
        cy = __fmul_rn(__fadd_rn(ymin, ymax), 0.5f);
        w  = fmaxf(__fsub_rn(xmax, xmin), 1e-6f);
        h  = fmaxf(__fsub_rn(ymax, ymin), 1e-6f);
        rw = 1.0f / w;                               // RN reciprocal for Markstein
        rh = 1.0f / h;
        float gf = __fmul_rn(__fadd_rn(log2f(__fmul_rn(w, 0.25f)),
                                       log2f(__fmul_rn(h, 0.25f))), 0.5f);
        int gl = (int)gf;
        gl = min(max(gl, lmin), lmax);
        gbin = min(max(gl - 3, 0), 4);
    }
    int grank = 0;
    if (t < 256) {                                   // waves 0..3 fully active
        #pragma unroll
        for (int bb = 0; bb < 5; ++bb) {
            unsigned long long m = __ballot(gbin == bb);
            if (gbin == bb) grank = __popcll(m & ((1ull << lane) - 1ull));
            if (lane == 0) s_gwh[wv][bb] = __popcll(m);
        }
    }
    __syncthreads();                                 // scatter + gt ballots complete
    if (t < 5) {
        int run = 0;
        for (int w2 = 0; w2 < 4; ++w2) { s_gwb[w2][t] = run; run += s_gwh[w2][t]; }
        s_gcnt[t] = run;
    }
    __syncthreads();
    if (t < K) {
        int base = 0;
        for (int bb = 0; bb < gbin; ++bb) base += s_gcnt[bb];
        int slot = base + s_gwb[wv][gbin] + grank;   // level-sorted permutation of 0..K-1
        s_cx[slot] = cx; s_cy[slot] = cy;
        s_w[slot] = w;   s_h[slot] = h;
        s_rw[slot] = rw; s_rh[slot] = rh;
        s_org[slot] = t; s_gbin[slot] = gbin;
    }
    __syncthreads();

    // phase E: scan this gt's level bucket (round-5 champion form; broadcast LDS reads)
    const int c = t >> 8, g = t & 255;
    unsigned long long bp = ~0ull;
    if (g < K) {
        float gcx = s_cx[g], gcy = s_cy[g];
        float gw = s_w[g], gh = s_h[g], grw = s_rw[g], grh = s_rh[g];
        int gbin2 = s_gbin[g];
        int base = 0;
        for (int bb = 0; bb < gbin2; ++bb) base += s_pcnt[bb];
        int cnt = s_pcnt[gbin2];
        int seg = (cnt + 3) >> 2;
        int i0 = c * seg, i1 = min(i0 + seg, cnt);
        #pragma unroll 4
        for (int ii = i0; ii < i1; ++ii) {
            float4 q = sp[base + ii];
            float dx = __fsub_rn(q.x, gcx);
            float dy = __fsub_rn(q.y, gcy);
            float qx = __fmul_rn(dx, grw);           // Markstein: == __fdiv_rn(dx, gw)
            qx = __fmaf_rn(__fmaf_rn(-gw, qx, dx), grw, qx);
            float qy = __fmul_rn(dy, grh);
            qy = __fmaf_rn(__fmaf_rn(-gh, qy, dy), grh, qy);
            float s = __fadd_rn(__fmul_rn(qx, qx), __fmul_rn(qy, qy));
            float d = __fsqrt_rn(s);
            unsigned long long cand =
                ((unsigned long long)__float_as_uint(d) << 32)
                | (unsigned)__float_as_int(q.z);
            bp = cand < bp ? cand : bp;              // lex-min (d, idx)
        }
    }

    // phase F: merge 4 copies, plain store to this block's private row (ORIGINAL gt idx)
    sh_p[t] = bp;
    __syncthreads();
    if (t < K) {
        unsigned long long p0 = sh_p[t];
        #pragma unroll
        for (int cc = 1; cc < 4; ++cc) {
            unsigned long long p1 = sh_p[cc * 256 + t];
            p0 = p1 < p0 ? p1 : p0;
        }
        pack2[(size_t)b * KMAX + s_org[t]] = p0;
    }
}

// ---------- C: grid reduce + contention resolve via LDS hash + scatter ----------
__global__ __launch_bounds__(1024)
void k_final(const unsigned long long* __restrict__ pack2,
             const int* __restrict__ glab, int* __restrict__ out,
             int N, int K, int nrows) {
    __shared__ unsigned long long sh_p[1024];
    __shared__ int hkey[512];
    __shared__ unsigned long long hval[512];
    const int t = threadIdx.x;
    const int c = t >> 8, k = t & 255;

    if (t < 512) { hkey[t] = -1; hval[t] = ~0ull; }

    // reduce over block rows (coalesced 512B per wave per iter)
    unsigned long long best = ~0ull;
    #pragma unroll 8
    for (int b = c; b < nrows; b += 4) {
        unsigned long long v = pack2[(size_t)b * KMAX + k];
        best = v < best ? v : best;
    }
    sh_p[t] = best;
    __syncthreads();

    if (t < 256) {
        unsigned long long p = sh_p[t];
        #pragma unroll
        for (int cc = 1; cc < 4; ++cc) {
            unsigned long long p1 = sh_p[cc * 256 + t];
            p = p1 < p ? p1 : p;
        }
        unsigned db = (unsigned)(p >> 32);
        bool valid = (t < K) && (db < 0x7F800000u);
        int nk = (int)(unsigned)(p & 0xFFFFFFFFu);

        int h = 0;
        if (valid) {
            unsigned long long myp = ((unsigned long long)db << 32) | (unsigned)t;
            h = (int)((((unsigned)nk) * 2654435761u) >> 23) & 511;
            while (true) {
                int old = atomicCAS(&hkey[h], -1, nk);
                if (old == -1 || old == nk) { atomicMin(&hval[h], myp); break; }
                h = (h + 1) & 511;
            }
        }
        __syncthreads();
        if (valid && (int)(unsigned)(hval[h] & 0xFFFFFFFFu) == t) {
            out[nk]     = t + 1;
            out[N + nk] = glab[t];
        }
    } else {
        __syncthreads();
    }
}

extern "C" void kernel_launch(void* const* d_in, const int* in_sizes, int n_in,
                              void* d_out, int out_size, void* d_ws, size_t ws_size,
                              hipStream_t stream) {
    const float* pts = (const float*)d_in[0];
    const float* gtb = (const float*)d_in[1];
    const int*  glab = (const int*)d_in[2];
    int N = in_sizes[0] / 3;
    int K = in_sizes[1] / 8;
    unsigned long long* pack2 = (unsigned long long*)d_ws;
    int nrows = (N + 1023) / 1024;

    k_dist<<<nrows, 1024, 0, stream>>>(pts, gtb, pack2, (int*)d_out, N, K);
    k_final<<<1, 1024, 0, stream>>>(pack2, glab, (int*)d_out, N, K, nrows);
}

// Round 10
// 27.122 us; speedup vs baseline: 3.8542x; 1.0392x over previous
//
#include <hip/hip_runtime.h>
#include <cstdint>

#define INFIN __builtin_inff()
constexpr int KMAX = 256;
constexpr int TPB  = 4;      // tiles (of 1024 points) per block
constexpr int NSL  = 4;      // gt slices of 64

// ws layout: u64 pack2[npg*256] @ 0  (npg = ceil(N/4096); 128 KB at N=256K)

// ---------- B: 4-tile scan of one 64-gt slice + private row-slice store ----------
__global__ __launch_bounds__(1024)
void k_dist(const float* __restrict__ pts, const float* __restrict__ gtb,
            unsigned long long* __restrict__ pack2, int* __restrict__ out,
            int N, int K, int npg) {
    const int t = threadIdx.x, b = blockIdx.x;
    const int pg = b >> 2, sl = b & 3;
    const int wv = t >> 6, lane = t & 63;

    __shared__ float4 sp[1024];                     // bucketed points (x,y,idx_bits,pad)
    __shared__ float s_cx[KMAX], s_cy[KMAX], s_w[KMAX], s_h[KMAX], s_rw[KMAX], s_rh[KMAX];
    __shared__ int   s_org[KMAX], s_gbin[KMAX];
    __shared__ int   s_wh[16][5], s_wb[16][5], s_pcnt[5];
    __shared__ int   s_gwh[4][5], s_gwb[4][5], s_gcnt[5];
    __shared__ unsigned long long sh_p[1024];

    // per-thread gt registers (set during tile 0)
    float gcx = 0.f, gcy = 0.f, gw = 1.f, gh = 1.f, grw = 1.f, grh = 1.f;
    int gbin2 = 0;
    bool gact = false;
    unsigned long long bp = ~0ull;

    for (int tt = 0; tt < TPB; ++tt) {
        // phase A: load tile point; zero this tile's output slice
        int i = (pg * TPB + tt) * 1024 + t;
        bool act = (i < N);
        float px = 0.f, py = 0.f;
        int pbin = -1;
        if (act) {
            px = pts[3 * i]; py = pts[3 * i + 1];
            unsigned u = __float_as_uint(pts[3 * i + 2]);
            int e = (int)((u >> 23) & 0xFF) - 127;  // exact log2 (stride = power of 2)
            pbin = e - 3;
            if (pbin < 0 || pbin > 4) pbin = -1;
            out[i] = 0; out[N + i] = 0;             // k_final scatters next dispatch
        }

        // phase B: per-wave level histogram + stable rank
        int prank = 0;
        #pragma unroll
        for (int bb = 0; bb < 5; ++bb) {
            unsigned long long m = __ballot(pbin == bb);
            if (pbin == bb) prank = __popcll(m & ((1ull << lane) - 1ull));
            if (lane == 0) s_wh[wv][bb] = __popcll(m);
        }
        __syncthreads();                            // also: all scans of tile tt-1 done
        if (t < 5) {
            int run = 0;
            for (int w2 = 0; w2 < 16; ++w2) { s_wb[w2][t] = run; run += s_wh[w2][t]; }
            s_pcnt[t] = run;
        }
        __syncthreads();

        // phase C: scatter point into its level bucket in LDS
        if (pbin >= 0) {
            int base = 0;
            for (int bb = 0; bb < pbin; ++bb) base += s_pcnt[bb];
            sp[base + s_wb[wv][pbin] + prank] = make_float4(px, py, __int_as_float(i), 0.f);
        }

        if (tt == 0) {
            // phase D (once): gt prep using tile-0 occupancy min/max (validated r9)
            int lmin = 127, lmax = -127;
            #pragma unroll
            for (int bb = 0; bb < 5; ++bb) {
                if (s_pcnt[bb] > 0) { lmin = min(lmin, bb + 3); lmax = max(lmax, bb + 3); }
            }
            float cx = 0.f, cy = 0.f, w = 1.f, h = 1.f, rw = 1.f, rh = 1.f;
            int gbin = 99;
            if (t < K) {
                float x0 = gtb[8*t+0], y0 = gtb[8*t+1], x1 = gtb[8*t+2], y1 = gtb[8*t+3];
                float x2 = gtb[8*t+4], y2 = gtb[8*t+5], x3 = gtb[8*t+6], y3 = gtb[8*t+7];
                float xmin = fminf(fminf(x0, x1), fminf(x2, x3));
                float xmax = fmaxf(fmaxf(x0, x1), fmaxf(x2, x3));
                float ymin = fminf(fminf(y0, y1), fminf(y2, y3));
                float ymax = fmaxf(fmaxf(y0, y1), fmaxf(y2, y3));
                cx = __fmul_rn(__fadd_rn(xmin, xmax), 0.5f);
                cy = __fmul_rn(__fadd_rn(ymin, ymax), 0.5f);
                w  = fmaxf(__fsub_rn(xmax, xmin), 1e-6f);
                h  = fmaxf(__fsub_rn(ymax, ymin), 1e-6f);
                rw = 1.0f / w;                       // RN reciprocal for Markstein
                rh = 1.0f / h;
                float gf = __fmul_rn(__fadd_rn(log2f(__fmul_rn(w, 0.25f)),
                                               log2f(__fmul_rn(h, 0.25f))), 0.5f);
                int gl = (int)gf;
                gl = min(max(gl, lmin), lmax);
                gbin = min(max(gl - 3, 0), 4);
            }
            int grank = 0;
            if (t < 256) {                           // waves 0..3 fully active
                #pragma unroll
                for (int bb = 0; bb < 5; ++bb) {
                    unsigned long long m = __ballot(gbin == bb);
                    if (gbin == bb) grank = __popcll(m & ((1ull << lane) - 1ull));
                    if (lane == 0) s_gwh[wv][bb] = __popcll(m);
                }
            }
            __syncthreads();
            if (t < 5) {
                int run = 0;
                for (int w2 = 0; w2 < 4; ++w2) { s_gwb[w2][t] = run; run += s_gwh[w2][t]; }
                s_gcnt[t] = run;
            }
            __syncthreads();
            if (t < K) {
                int base = 0;
                for (int bb = 0; bb < gbin; ++bb) base += s_gcnt[bb];
                int slot = base + s_gwb[wv][gbin] + grank;  // level-sorted permutation
                s_cx[slot] = cx; s_cy[slot] = cy;
                s_w[slot] = w;   s_h[slot] = h;
                s_rw[slot] = rw; s_rh[slot] = rh;
                s_org[slot] = t; s_gbin[slot] = gbin;
            }
            __syncthreads();
            // load this thread's gt registers (persist across tiles)
            int slot = sl * 64 + (t & 63);
            gact = slot < K;
            if (gact) {
                gcx = s_cx[slot]; gcy = s_cy[slot];
                gw = s_w[slot];  gh = s_h[slot];
                grw = s_rw[slot]; grh = s_rh[slot];
                gbin2 = s_gbin[slot];
            }
        } else {
            __syncthreads();                         // scatter -> scan protection
        }

        // phase E: scan this gt's level bucket in this tile (broadcast LDS reads)
        if (gact) {
            const int c = t >> 6;                    // 16 copies per gt
            int base = 0;
            for (int bb = 0; bb < gbin2; ++bb) base += s_pcnt[bb];
            int cnt = s_pcnt[gbin2];
            int seg = (cnt + 15) >> 4;
            int i0 = c * seg, i1 = min(i0 + seg, cnt);
            #pragma unroll 4
            for (int ii = i0; ii < i1; ++ii) {
                float4 q = sp[base + ii];
                float dx = __fsub_rn(q.x, gcx);
                float dy = __fsub_rn(q.y, gcy);
                float qx = __fmul_rn(dx, grw);       // Markstein: == __fdiv_rn(dx, gw)
                qx = __fmaf_rn(__fmaf_rn(-gw, qx, dx), grw, qx);
                float qy = __fmul_rn(dy, grh);
                qy = __fmaf_rn(__fmaf_rn(-gh, qy, dy), grh, qy);
                float s = __fadd_rn(__fmul_rn(qx, qx), __fmul_rn(qy, qy));
                float d = __fsqrt_rn(s);
                unsigned long long cand =
                    ((unsigned long long)__float_as_uint(d) << 32)
                    | (unsigned)__float_as_int(q.z);
                bp = cand < bp ? cand : bp;          // lex-min (d, idx)
            }
        }
    }

    // phase F: merge 16 copies; store this block's 64-entry row slice (ORIGINAL gt idx)
    sh_p[t] = bp;
    __syncthreads();
    if (t < 64) {
        unsigned long long p0 = sh_p[t];
        #pragma unroll
        for (int cc = 1; cc < 16; ++cc) {
            unsigned long long p1 = sh_p[cc * 64 + t];
            p0 = p1 < p0 ? p1 : p0;
        }
        int slot = sl * 64 + t;
        if (slot < K) pack2[(size_t)pg * KMAX + s_org[slot]] = p0;
    }
}

// ---------- C: row reduce + contention resolve via LDS hash + scatter ----------
__global__ __launch_bounds__(1024)
void k_final(const unsigned long long* __restrict__ pack2,
             const int* __restrict__ glab, int* __restrict__ out,
             int N, int K, int nrows) {
    __shared__ unsigned long long sh_p[1024];
    __shared__ int hkey[512];
    __shared__ unsigned long long hval[512];
    const int t = threadIdx.x;
    const int c = t >> 8, k = t & 255;

    if (t < 512) { hkey[t] = -1; hval[t] = ~0ull; }

    // reduce over rows (coalesced 512B per wave per iter)
    unsigned long long best = ~0ull;
    #pragma unroll 8
    for (int r = c; r < nrows; r += 4) {
        unsigned long long v = pack2[(size_t)r * KMAX + k];
        best = v < best ? v : best;
    }
    sh_p[t] = best;
    __syncthreads();

    if (t < 256) {
        unsigned long long p = sh_p[t];
        #pragma unroll
        for (int cc = 1; cc < 4; ++cc) {
            unsigned long long p1 = sh_p[cc * 256 + t];
            p = p1 < p ? p1 : p;
        }
        unsigned db = (unsigned)(p >> 32);
        bool valid = (t < K) && (db < 0x7F800000u);
        int nk = (int)(unsigned)(p & 0xFFFFFFFFu);

        int h = 0;
        if (valid) {
            unsigned long long myp = ((unsigned long long)db << 32) | (unsigned)t;
            h = (int)((((unsigned)nk) * 2654435761u) >> 23) & 511;
            while (true) {
                int old = atomicCAS(&hkey[h], -1, nk);
                if (old == -1 || old == nk) { atomicMin(&hval[h], myp); break; }
                h = (h + 1) & 511;
            }
        }
        __syncthreads();
        if (valid && (int)(unsigned)(hval[h] & 0xFFFFFFFFu) == t) {
            out[nk]     = t + 1;
            out[N + nk] = glab[t];
        }
    } else {
        __syncthreads();
    }
}

extern "C" void kernel_launch(void* const* d_in, const int* in_sizes, int n_in,
                              void* d_out, int out_size, void* d_ws, size_t ws_size,
                              hipStream_t stream) {
    const float* pts = (const float*)d_in[0];
    const float* gtb = (const float*)d_in[1];
    const int*  glab = (const int*)d_in[2];
    int N = in_sizes[0] / 3;
    int K = in_sizes[1] / 8;
    unsigned long long* pack2 = (unsigned long long*)d_ws;
    int npg = (N + TPB * 1024 - 1) / (TPB * 1024);

    k_dist<<<npg * NSL, 1024, 0, stream>>>(pts, gtb, pack2, (int*)d_out, N, K, npg);
    k_final<<<1, 1024, 0, stream>>>(pack2, glab, (int*)d_out, N, K, npg);
}

// Round 11
// 26.459 us; speedup vs baseline: 3.9509x; 1.0251x over previous
//
#include <hip/hip_runtime.h>
#include <cstdint>

#define INFIN __builtin_inff()
constexpr int KMAX = 256;
constexpr int TPB  = 2;      // tiles (of 1024 points) per block
constexpr int NSL  = 4;      // gt slices of 64

// ws layout: u64 pack2[npg*256] @ 0  (npg = ceil(N/2048); 256 KB at N=256K)

// ---------- B: 2-tile scan of one 64-gt slice + private row-slice store ----------
__global__ __launch_bounds__(1024)
void k_dist(const float* __restrict__ pts, const float* __restrict__ gtb,
            unsigned long long* __restrict__ pack2, int* __restrict__ out,
            int N, int K, int npg) {
    const int t = threadIdx.x, b = blockIdx.x;
    const int pg = b >> 2, sl = b & 3;
    const int wv = t >> 6, lane = t & 63;

    __shared__ float4 sp[1024];                     // bucketed points (x,y,idx_bits,pad)
    __shared__ float s_cx[KMAX], s_cy[KMAX], s_w[KMAX], s_h[KMAX], s_rw[KMAX], s_rh[KMAX];
    __shared__ int   s_org[KMAX], s_gbin[KMAX];
    __shared__ int   s_wh[16][5], s_wb[16][5], s_pcnt[5];
    __shared__ int   s_gwh[4][5], s_gwb[4][5], s_gcnt[5];
    __shared__ unsigned long long sh_p[1024];

    // per-thread gt registers (set during tile 0)
    float gcx = 0.f, gcy = 0.f, gw = 1.f, gh = 1.f, grw = 1.f, grh = 1.f;
    int gbin2 = 0;
    bool gact = false;
    unsigned long long bp = ~0ull;

    for (int tt = 0; tt < TPB; ++tt) {
        // phase A: load tile point (zeroing deferred to kernel exit)
        int i = (pg * TPB + tt) * 1024 + t;
        bool act = (i < N);
        float px = 0.f, py = 0.f;
        int pbin = -1;
        if (act) {
            px = pts[3 * i]; py = pts[3 * i + 1];
            unsigned u = __float_as_uint(pts[3 * i + 2]);
            int e = (int)((u >> 23) & 0xFF) - 127;  // exact log2 (stride = power of 2)
            pbin = e - 3;
            if (pbin < 0 || pbin > 4) pbin = -1;
        }

        // phase B: per-wave level histogram + stable rank
        int prank = 0;
        #pragma unroll
        for (int bb = 0; bb < 5; ++bb) {
            unsigned long long m = __ballot(pbin == bb);
            if (pbin == bb) prank = __popcll(m & ((1ull << lane) - 1ull));
            if (lane == 0) s_wh[wv][bb] = __popcll(m);
        }
        __syncthreads();                            // also: all scans of tile tt-1 done
        if (t < 5) {
            int run = 0;
            for (int w2 = 0; w2 < 16; ++w2) { s_wb[w2][t] = run; run += s_wh[w2][t]; }
            s_pcnt[t] = run;
        }
        __syncthreads();

        // phase C: scatter point into its level bucket in LDS
        if (pbin >= 0) {
            int base = 0;
            for (int bb = 0; bb < pbin; ++bb) base += s_pcnt[bb];
            sp[base + s_wb[wv][pbin] + prank] = make_float4(px, py, __int_as_float(i), 0.f);
        }

        if (tt == 0) {
            // phase D (once): gt prep using tile-0 occupancy min/max (validated r9/r10)
            int lmin = 127, lmax = -127;
            #pragma unroll
            for (int bb = 0; bb < 5; ++bb) {
                if (s_pcnt[bb] > 0) { lmin = min(lmin, bb + 3); lmax = max(lmax, bb + 3); }
            }
            float cx = 0.f, cy = 0.f, w = 1.f, h = 1.f, rw = 1.f, rh = 1.f;
            int gbin = 99;
            if (t < K) {
                float x0 = gtb[8*t+0], y0 = gtb[8*t+1], x1 = gtb[8*t+2], y1 = gtb[8*t+3];
                float x2 = gtb[8*t+4], y2 = gtb[8*t+5], x3 = gtb[8*t+6], y3 = gtb[8*t+7];
                float xmin = fminf(fminf(x0, x1), fminf(x2, x3));
                float xmax = fmaxf(fmaxf(x0, x1), fmaxf(x2, x3));
                float ymin = fminf(fminf(y0, y1), fminf(y2, y3));
                float ymax = fmaxf(fmaxf(y0, y1), fmaxf(y2, y3));
                cx = __fmul_rn(__fadd_rn(xmin, xmax), 0.5f);
                cy = __fmul_rn(__fadd_rn(ymin, ymax), 0.5f);
                w  = fmaxf(__fsub_rn(xmax, xmin), 1e-6f);
                h  = fmaxf(__fsub_rn(ymax, ymin), 1e-6f);
                rw = 1.0f / w;                       // RN reciprocal for Markstein
                rh = 1.0f / h;
                float gf = __fmul_rn(__fadd_rn(log2f(__fmul_rn(w, 0.25f)),
                                               log2f(__fmul_rn(h, 0.25f))), 0.5f);
                int gl = (int)gf;
                gl = min(max(gl, lmin), lmax);
                gbin = min(max(gl - 3, 0), 4);
            }
            int grank = 0;
            if (t < 256) {                           // waves 0..3 fully active
                #pragma unroll
                for (int bb = 0; bb < 5; ++bb) {
                    unsigned long long m = __ballot(gbin == bb);
                    if (gbin == bb) grank = __popcll(m & ((1ull << lane) - 1ull));
                    if (lane == 0) s_gwh[wv][bb] = __popcll(m);
                }
            }
            __syncthreads();
            if (t < 5) {
                int run = 0;
                for (int w2 = 0; w2 < 4; ++w2) { s_gwb[w2][t] = run; run += s_gwh[w2][t]; }
                s_gcnt[t] = run;
            }
            __syncthreads();
            if (t < K) {
                int base = 0;
                for (int bb = 0; bb < gbin; ++bb) base += s_gcnt[bb];
                int slot = base + s_gwb[wv][gbin] + grank;  // level-sorted permutation
                s_cx[slot] = cx; s_cy[slot] = cy;
                s_w[slot] = w;   s_h[slot] = h;
                s_rw[slot] = rw; s_rh[slot] = rh;
                s_org[slot] = t; s_gbin[slot] = gbin;
            }
            __syncthreads();
            // load this thread's gt registers (persist across tiles)
            int slot = sl * 64 + (t & 63);
            gact = slot < K;
            if (gact) {
                gcx = s_cx[slot]; gcy = s_cy[slot];
                gw = s_w[slot];  gh = s_h[slot];
                grw = s_rw[slot]; grh = s_rh[slot];
                gbin2 = s_gbin[slot];
            }
        } else {
            __syncthreads();                         // scatter -> scan protection
        }

        // phase E: scan this gt's level bucket in this tile (broadcast LDS reads)
        if (gact) {
            const int c = t >> 6;                    // 16 copies per gt
            int base = 0;
            for (int bb = 0; bb < gbin2; ++bb) base += s_pcnt[bb];
            int cnt = s_pcnt[gbin2];
            int seg = (cnt + 15) >> 4;
            int i0 = c * seg, i1 = min(i0 + seg, cnt);
            #pragma unroll 4
            for (int ii = i0; ii < i1; ++ii) {
                float4 q = sp[base + ii];
                float dx = __fsub_rn(q.x, gcx);
                float dy = __fsub_rn(q.y, gcy);
                float qx = __fmul_rn(dx, grw);       // Markstein: == __fdiv_rn(dx, gw)
                qx = __fmaf_rn(__fmaf_rn(-gw, qx, dx), grw, qx);
                float qy = __fmul_rn(dy, grh);
                qy = __fmaf_rn(__fmaf_rn(-gh, qy, dy), grh, qy);
                float s = __fadd_rn(__fmul_rn(qx, qx), __fmul_rn(qy, qy));
                float d = __fsqrt_rn(s);
                unsigned long long cand =
                    ((unsigned long long)__float_as_uint(d) << 32)
                    | (unsigned)__float_as_int(q.z);
                bp = cand < bp ? cand : bp;          // lex-min (d, idx)
            }
        }
    }

    // phase F: merge 16 copies; store this block's 64-entry row slice (ORIGINAL gt idx)
    sh_p[t] = bp;
    __syncthreads();
    if (t < 64) {
        unsigned long long p0 = sh_p[t];
        #pragma unroll
        for (int cc = 1; cc < 16; ++cc) {
            unsigned long long p1 = sh_p[cc * 64 + t];
            p0 = p1 < p0 ? p1 : p0;
        }
        int slot = sl * 64 + t;
        if (slot < K) pack2[(size_t)pg * KMAX + s_org[slot]] = p0;
    }

    // deferred: zero this block's output slice (no barrier follows; drains at exit)
    #pragma unroll
    for (int tt = 0; tt < TPB; ++tt) {
        int i = (pg * TPB + tt) * 1024 + t;
        if (i < N) { out[i] = 0; out[N + i] = 0; }
    }
}

// ---------- C: row reduce + contention resolve via LDS hash + scatter ----------
__global__ __launch_bounds__(1024)
void k_final(const unsigned long long* __restrict__ pack2,
             const int* __restrict__ glab, int* __restrict__ out,
             int N, int K, int nrows) {
    __shared__ unsigned long long sh_p[1024];
    __shared__ int hkey[512];
    __shared__ unsigned long long hval[512];
    const int t = threadIdx.x;
    const int c = t >> 8, k = t & 255;

    if (t < 512) { hkey[t] = -1; hval[t] = ~0ull; }

    // reduce over rows (coalesced 512B per wave per iter)
    unsigned long long best = ~0ull;
    #pragma unroll 8
    for (int r = c; r < nrows; r += 4) {
        unsigned long long v = pack2[(size_t)r * KMAX + k];
        best = v < best ? v : best;
    }
    sh_p[t] = best;
    __syncthreads();

    if (t < 256) {
        unsigned long long p = sh_p[t];
        #pragma unroll
        for (int cc = 1; cc < 4; ++cc) {
            unsigned long long p1 = sh_p[cc * 256 + t];
            p = p1 < p ? p1 : p;
        }
        unsigned db = (unsigned)(p >> 32);
        bool valid = (t < K) && (db < 0x7F800000u);
        int nk = (int)(unsigned)(p & 0xFFFFFFFFu);

        int h = 0;
        if (valid) {
            unsigned long long myp = ((unsigned long long)db << 32) | (unsigned)t;
            h = (int)((((unsigned)nk) * 2654435761u) >> 23) & 511;
            while (true) {
                int old = atomicCAS(&hkey[h], -1, nk);
                if (old == -1 || old == nk) { atomicMin(&hval[h], myp); break; }
                h = (h + 1) & 511;
            }
        }
        __syncthreads();
        if (valid && (int)(unsigned)(hval[h] & 0xFFFFFFFFu) == t) {
            out[nk]     = t + 1;
            out[N + nk] = glab[t];
        }
    } else {
        __syncthreads();
    }
}

extern "C" void kernel_launch(void* const* d_in, const int* in_sizes, int n_in,
                              void* d_out, int out_size, void* d_ws, size_t ws_size,
                              hipStream_t stream) {
    const float* pts = (const float*)d_in[0];
    const float* gtb = (const float*)d_in[1];
    const int*  glab = (const int*)d_in[2];
    int N = in_sizes[0] / 3;
    int K = in_sizes[1] / 8;
    unsigned long long* pack2 = (unsigned long long*)d_ws;
    int npg = (N + TPB * 1024 - 1) / (TPB * 1024);

    k_dist<<<npg * NSL, 1024, 0, stream>>>(pts, gtb, pack2, (int*)d_out, N, K, npg);
    k_final<<<1, 1024, 0, stream>>>(pack2, glab, (int*)d_out, N, K, npg);
}